// Round 18
// baseline (119.656 us; speedup 1.0000x reference)
//
#include <hip/hip_runtime.h>
#include <stdint.h>

typedef _Float16 f16x8 __attribute__((ext_vector_type(8)));
typedef float    f32x4 __attribute__((ext_vector_type(4)));

#define RBITS 9
#define RSZ   512         // nodes per bucket
#define G     512         // edge chunks (one block each)
#define MAXB  256         // max buckets (N <= 131072; s fits 17 bits)
#define CHMAX 3200        // >= ceil(E/G) = 3125
#define RMAX  7           // ceil(CHMAX/512)

#define NTL(p) __builtin_nontemporal_load(p)
#define NTS(v, p) __builtin_nontemporal_store(v, p)

// ---- block-wide exclusive scan (shuffles + wave totals); NT = block size ----
template<int NT>
__device__ __forceinline__ uint32_t scanExcl(uint32_t v, uint32_t* wtot, int t)
{
    uint32_t x = v;
    #pragma unroll
    for (int d = 1; d < 64; d <<= 1) {
        uint32_t y = __shfl_up(x, d, 64);
        if ((t & 63) >= d) x += y;
    }
    int w = t >> 6;
    if ((t & 63) == 63) wtot[w] = x;
    __syncthreads();
    uint32_t pre = 0;
    #pragma unroll
    for (int k = 0; k < NT / 64; ++k) pre += (k < w) ? wtot[k] : 0;
    return pre + x - v;
}

// ------- fused node+count: grid = G blocks; all count, low blocks do node ----
__global__ __launch_bounds__(512) void nodecount_kernel(
    const int*   __restrict__ features,
    const float* __restrict__ cars,
    const float* __restrict__ entered,
    const float* __restrict__ free_,
    const float* __restrict__ embed_table,
    const float* __restrict__ W2n,   // 33
    const float* __restrict__ b2n,   // 1
    const float* __restrict__ W2e,   // 64x32
    const float* __restrict__ W3,    // 35x8
    const int* __restrict__ src, const int* __restrict__ dst,
    float* __restrict__ emb_out,     // N x 32
    float* __restrict__ cars1,       // N
    f16x8* __restrict__ Ah,          // N
    f16x8* __restrict__ Bh,          // N
    float* __restrict__ sfree,       // N: sign = free, magnitude = feature+1
    uint16_t* __restrict__ cntS, uint16_t* __restrict__ cntD,  // [B][G]
    int N, int E, int B)
{
    __shared__ uint32_t cS[MAXB], cD[MAXB];
    int t = threadIdx.x, g = blockIdx.x;
    for (int i = t; i < MAXB; i += 512) { cS[i] = 0; cD[i] = 0; }
    __syncthreads();
    int per = (E + G - 1) / G;
    int lo = g * per, hi = min(E, lo + per);
    for (int i = lo + t; i < hi; i += 512) {
        atomicAdd(&cS[NTL(&src[i]) >> RBITS], 1u);
        atomicAdd(&cD[NTL(&dst[i]) >> RBITS], 1u);
    }
    __syncthreads();
    for (int i = t; i < B; i += 512) {
        cntS[(size_t)i * G + g] = (uint16_t)cS[i];
        cntD[(size_t)i * G + g] = (uint16_t)cD[i];
    }

    // ---- node part (blocks covering node range only) ----
    if (g * 512 >= N) return;
    __shared__ float Wa[256], Wb[256];
    if (t < 256) {
        int k = t >> 3, j = t & 7;   // t == k*8+j
        float a = 0.f, b = 0.f;
        #pragma unroll
        for (int m = 0; m < 32; ++m) {
            float w3 = W3[m * 8 + j];
            a += W2e[k * 32 + m]        * w3;
            b += W2e[(32 + k) * 32 + m] * w3;
        }
        Wa[t] = a;
        Wb[t] = b;
    }
    __syncthreads();

    int i = g * 512 + t;
    if (i >= N) return;
    int f = features[i];
    const f32x4* erow = (const f32x4*)(embed_table + (size_t)f * 32);
    f32x4* orow = (f32x4*)(emb_out + (size_t)i * 32);
    float e[32];
    #pragma unroll
    for (int q = 0; q < 8; ++q) {
        f32x4 v = erow[q];
        NTS(v, &orow[q]);                      // emb_out never re-read
        e[4*q+0] = v.x; e[4*q+1] = v.y; e[4*q+2] = v.z; e[4*q+3] = v.w;
    }
    float parked = b2n[0];
    #pragma unroll
    for (int k = 0; k < 32; ++k) parked += e[k] * W2n[k];
    float c = cars[i];
    parked += c * W2n[32];
    float c1 = fmaxf(fmaxf(parked, 0.f) + c, 0.f);
    cars1[i] = c1;
    float fm = (float)f + 1.f;                   // exact (< 2^24)
    sfree[i] = (free_[i] > 0.5f) ? -fm : fm;

    float ent = entered[i];
    float a8[8], b8[8];
    #pragma unroll
    for (int j = 0; j < 8; ++j) {
        a8[j] = c1 * W3[32*8 + j] + ent * W3[34*8 + j];
        b8[j] = c1 * W3[33*8 + j];
    }
    #pragma unroll
    for (int k = 0; k < 32; ++k) {
        float x = e[k];
        #pragma unroll
        for (int j = 0; j < 8; ++j) {
            a8[j] += x * Wa[k*8 + j];
            b8[j] += x * Wb[k*8 + j];
        }
    }
    f16x8 av, bv;
    #pragma unroll
    for (int j = 0; j < 8; ++j) { av[j] = (_Float16)a8[j]; bv[j] = (_Float16)b8[j]; }
    Ah[i] = av;
    Bh[i] = bv;
}

// -------- scanA: per-bucket exclusive scan over G chunks (1 block/bucket) ----
__global__ __launch_bounds__(512) void scanA_kernel(
    uint16_t* __restrict__ cntS, uint16_t* __restrict__ cntD,
    uint32_t* __restrict__ totS, uint32_t* __restrict__ totD, int B)
{
    __shared__ uint32_t wtot[8];
    int arr = (int)(blockIdx.x >= (unsigned)B);
    int b = blockIdx.x - (arr ? B : 0);
    uint16_t* a   = arr ? cntD : cntS;
    uint32_t* tot = arr ? totD : totS;
    int t = threadIdx.x;
    uint32_t v = a[(size_t)b * G + t];
    uint32_t e = scanExcl<512>(v, wtot, t);
    a[(size_t)b * G + t] = (uint16_t)e;
    if (t == G - 1) tot[b] = e + v;
}

// -------- scatter (fused): edge MLP once; bin by src AND by dst --------------
// Streaming (src/dst reads, payload/metaEx writes) is NON-TEMPORAL so the
// gathered node arrays (Ah/Bh/sfree, 3.6MB) stay resident in per-XCD L2.
__global__ __launch_bounds__(512) void scatter_kernel(
    const int* __restrict__ src, const int* __restrict__ dst,
    const float* __restrict__ sfree,
    const f16x8* __restrict__ Ah, const f16x8* __restrict__ Bh,
    const float* __restrict__ b2e, const float* __restrict__ W3,
    const float* __restrict__ b3,  const float* __restrict__ W4,
    const float* __restrict__ b4,
    const uint16_t* __restrict__ cntS, const uint16_t* __restrict__ cntD,
    const uint32_t* __restrict__ totS, const uint32_t* __restrict__ totD,
    uint32_t* __restrict__ payloadS,   // E : s_local | exb<<16
    uint64_t* __restrict__ metaEx,     // E : (s | dloc<<17 | self<<31) | exb<<32
    int E, int B)
{
    __shared__ float b3p[8];
    __shared__ uint32_t curS[MAXB], curD[MAXB];
    __shared__ uint32_t tblS[MAXB], tblD[MAXB];   // hcnt -> hbase (in place)
    __shared__ uint32_t wtot[8];
    __shared__ union { uint32_t b32[CHMAX]; uint64_t b64[CHMAX]; } stg;
    __shared__ uint16_t bid[CHMAX];

    int t = threadIdx.x, g = blockIdx.x;
    // base prefixes from totals (values only on t < B <= 256)
    uint32_t vS = (t < B) ? totS[t] : 0;
    uint32_t eS = scanExcl<512>(vS, wtot, t);
    __syncthreads();
    uint32_t vD = (t < B) ? totD[t] : 0;
    uint32_t eD = scanExcl<512>(vD, wtot, t);
    if (t < B) {
        curS[t] = eS + cntS[(size_t)t * G + g];
        curD[t] = eD + cntD[(size_t)t * G + g];
    }
    if (t < MAXB) { tblS[t] = 0; tblD[t] = 0; }
    if (t < 8) {           // fold b2e@W3 into b3
        float s = b3[t];
        #pragma unroll
        for (int m = 0; m < 32; ++m) s += b2e[m] * W3[m * 8 + t];
        b3p[t] = s;
    }
    __syncthreads();
    float w4[8]; float bias4 = b4[0];
    #pragma unroll
    for (int j = 0; j < 8; ++j) w4[j] = W4[j];

    int per = (E + G - 1) / G;
    int lo = g * per, hi = min(E, lo + per), n = hi - lo;

    // regA = keyS | rankS<<8 | self<<31 ; regB = keyD | rankD<<8 | dloc<<21
    // regC = s_local | exb<<16    (ranks < 3200: bits 8..19)
    uint32_t regA[RMAX], regB[RMAX], regC[RMAX];
    #pragma unroll
    for (int r = 0; r < RMAX; ++r) {
        int idx = r * 512 + t;
        if (idx < n) {
            int i = lo + idx;
            int s = NTL(&src[i]), d = NTL(&dst[i]);
            f16x8 av = Ah[s], bv = Bh[d];
            float fsv = sfree[s];
            float fdv = sfree[d];
            float out = bias4;
            #pragma unroll
            for (int j = 0; j < 8; ++j)
                out += fmaxf((float)av[j] + (float)bv[j] + b3p[j], 0.f) * w4[j];
            bool self  = (fabsf(fsv) == fabsf(fdv));
            bool freeS = (fsv < 0.f);
            float l = (self != freeS) ? fmaxf(out, 0.f) : 0.f;
            float ex = __expf(l);             // l in [0,~6]: no overflow
            uint32_t exb = (uint32_t)__builtin_bit_cast(unsigned short, (_Float16)ex);
            uint32_t keyS = (uint32_t)s >> RBITS;
            uint32_t keyD = (uint32_t)d >> RBITS;
            uint32_t rankS = atomicAdd(&tblS[keyS], 1u);
            uint32_t rankD = atomicAdd(&tblD[keyD], 1u);
            regA[r] = keyS | (rankS << 8) | (self ? 0x80000000u : 0u);
            regB[r] = keyD | (rankD << 8) | ((uint32_t)(d & (RSZ - 1)) << 21);
            regC[r] = (uint32_t)(s & (RSZ - 1)) | (exb << 16);
        }
    }
    __syncthreads();
    uint32_t hS = (t < MAXB) ? tblS[t] : 0;
    uint32_t hD = (t < MAXB) ? tblD[t] : 0;
    __syncthreads();
    uint32_t bS = scanExcl<512>(hS, wtot, t);
    __syncthreads();
    uint32_t bD = scanExcl<512>(hD, wtot, t);
    if (t < MAXB) {
        tblS[t] = bS;      // now hbaseS
        tblD[t] = bD;      // now hbaseD
    }
    __syncthreads();

    // ---- phase S: place grouped (record bucket id), flush with computed addr
    #pragma unroll
    for (int r = 0; r < RMAX; ++r) {
        int idx = r * 512 + t;
        if (idx < n) {
            uint32_t key = regA[r] & 255u;
            uint32_t slot = tblS[key] + ((regA[r] >> 8) & 0xFFFu);
            stg.b32[slot] = regC[r];
            bid[slot] = (uint16_t)key;
        }
    }
    __syncthreads();
    for (int j = t; j < n; j += 512) {
        uint32_t b = bid[j];
        NTS(stg.b32[j], &payloadS[curS[b] + (j - tblS[b])]);
    }
    __syncthreads();

    // ---- phase D: u64 records, single staged flush ----
    #pragma unroll
    for (int r = 0; r < RMAX; ++r) {
        int idx = r * 512 + t;
        if (idx < n) {
            uint32_t key = regB[r] & 255u;
            uint32_t slot = tblD[key] + ((regB[r] >> 8) & 0xFFFu);
            uint32_t s = ((regA[r] & 255u) << RBITS) | (regC[r] & (RSZ - 1));
            uint32_t mlo = s | (((regB[r] >> 21) & 0x1FFu) << 17)
                         | (regA[r] & 0x80000000u);
            stg.b64[slot] = (uint64_t)mlo | ((uint64_t)(regC[r] >> 16) << 32);
            bid[slot] = (uint16_t)key;
        }
    }
    __syncthreads();
    for (int j = t; j < n; j += 512) {
        uint32_t b = bid[j];
        NTS(stg.b64[j], &metaEx[curD[b] + (j - tblD[b])]);
    }
}

// ---------------- bucketS: ssum via LDS, emit ratio = cars1/ssum -------------
__global__ __launch_bounds__(1024) void bucketS_kernel(
    const uint32_t* __restrict__ totS, const uint32_t* __restrict__ payloadS,
    const float* __restrict__ cars1, float* __restrict__ ratio,
    int N, int B)
{
    __shared__ float acc[RSZ];
    __shared__ uint32_t wtot[16];
    __shared__ uint32_t be[2];
    int b = blockIdx.x, t = threadIdx.x;
    uint32_t v = (t < B) ? totS[t] : 0;
    uint32_t e = scanExcl<1024>(v, wtot, t);
    if (t == b) { be[0] = e; be[1] = e + v; }
    for (int i = t; i < RSZ; i += 1024) acc[i] = 0.f;
    __syncthreads();
    uint32_t beg = be[0], end = be[1];
    for (uint32_t i = beg + t; i < end; i += 1024) {
        uint32_t p = NTL(&payloadS[i]);
        float val = (float)__builtin_bit_cast(_Float16, (unsigned short)(p >> 16));
        atomicAdd(&acc[p & (RSZ - 1)], val);       // ds_add_f32
    }
    __syncthreads();
    int nb = b << RBITS;
    for (int i = t; i < RSZ; i += 1024) {
        int node = nb + i;
        if (node < N) {
            float s = acc[i];
            ratio[node] = cars1[node] / (s > 0.f ? s : 1.f);  // unused if deg 0
        }
    }
}

// ------- bucketD: cars/delta via LDS, write cars_out & entered_out -----------
__global__ __launch_bounds__(1024) void bucketD_kernel(
    const uint32_t* __restrict__ totD,
    const uint64_t* __restrict__ metaEx,
    const float* __restrict__ ratio,
    float* __restrict__ cars_out, float* __restrict__ entered_out,
    int N, int B)
{
    __shared__ float accC[RSZ], accX[RSZ];
    __shared__ uint32_t wtot[16];
    __shared__ uint32_t be[2];
    int b = blockIdx.x, t = threadIdx.x;
    uint32_t v = (t < B) ? totD[t] : 0;
    uint32_t e = scanExcl<1024>(v, wtot, t);
    if (t == b) { be[0] = e; be[1] = e + v; }
    for (int i = t; i < RSZ; i += 1024) { accC[i] = 0.f; accX[i] = 0.f; }
    __syncthreads();
    uint32_t beg = be[0], end = be[1];
    for (uint32_t i = beg + t; i < end; i += 1024) {
        uint64_t me = NTL(&metaEx[i]);
        uint32_t m = (uint32_t)me;
        float ex = (float)__builtin_bit_cast(_Float16, (unsigned short)(me >> 32));
        int s  = m & 0x1FFFF;
        int ld = (m >> 17) & (RSZ - 1);
        float c = ratio[s] * ex;
        atomicAdd(&accC[ld], c);
        if (m & 0x80000000u) atomicAdd(&accX[ld], c);   // selfloop
    }
    __syncthreads();
    int nb = b << RBITS;
    for (int i = t; i < RSZ; i += 1024) {
        int node = nb + i;
        if (node < N) {
            float cs = accC[i];
            NTS(cs, &cars_out[node]);
            NTS(cs - accX[i], &entered_out[node]);
        }
    }
}

extern "C" void kernel_launch(void* const* d_in, const int* in_sizes, int n_in,
                              void* d_out, int out_size, void* d_ws, size_t ws_size,
                              hipStream_t stream)
{
    const int N = in_sizes[0];     // 100000
    const int E = in_sizes[4];     // 1600000
    const int B = (N + RSZ - 1) / RSZ;     // 196 buckets
    const int L = B * G;

    const int*   features    = (const int*)  d_in[0];
    const float* cars        = (const float*)d_in[1];
    const float* entered     = (const float*)d_in[2];
    const float* free_       = (const float*)d_in[3];
    const int*   src         = (const int*)  d_in[4];
    const int*   dst         = (const int*)  d_in[5];
    const float* embed_table = (const float*)d_in[6];
    const float* W2n         = (const float*)d_in[7];
    const float* b2n         = (const float*)d_in[8];
    const float* W2e         = (const float*)d_in[9];
    const float* b2e         = (const float*)d_in[10];
    const float* W3          = (const float*)d_in[11];
    const float* b3          = (const float*)d_in[12];
    const float* W4          = (const float*)d_in[13];
    const float* b4          = (const float*)d_in[14];

    float* out         = (float*)d_out;
    float* cars_out    = out;                       // N
    float* emb_out     = out + N;                   // N*32
    float* entered_out = out + (size_t)N * 33;      // N

    // workspace layout (float offsets; Ah at 4N -> 16B aligned)
    float*    ws       = (float*)d_ws;
    float*    cars1    = ws;                              // N
    float*    ratio    = ws + N;                          // N
    float*    sfree    = ws + (size_t)2 * N;              // N (signed feat)
    f16x8*    Ah       = (f16x8*)(ws + (size_t)4 * N);    // N*16B
    f16x8*    Bh       = (f16x8*)(ws + (size_t)8 * N);    // N*16B
    uint32_t* totS     = (uint32_t*)(ws + (size_t)12 * N);// B
    uint32_t* totD     = totS + MAXB;                     // B
    // metaEx first for 8B alignment (12N + 512 floats -> even)
    uint64_t* metaEx   = (uint64_t*)(totD + MAXB);        // E u64
    uint32_t* payloadS = (uint32_t*)(metaEx + E);         // E u32
    uint16_t* cntS     = (uint16_t*)(payloadS + E);       // L u16
    uint16_t* cntD     = cntS + L;                        // L u16

    nodecount_kernel<<<G, 512, 0, stream>>>(
        features, cars, entered, free_, embed_table, W2n, b2n, W2e, W3,
        src, dst, emb_out, cars1, Ah, Bh, sfree, cntS, cntD, N, E, B);
    scanA_kernel<<<2 * B, 512, 0, stream>>>(cntS, cntD, totS, totD, B);
    scatter_kernel<<<G, 512, 0, stream>>>(
        src, dst, sfree, Ah, Bh, b2e, W3, b3, W4, b4,
        cntS, cntD, totS, totD, payloadS, metaEx, E, B);
    bucketS_kernel<<<B, 1024, 0, stream>>>(totS, payloadS, cars1, ratio, N, B);
    bucketD_kernel<<<B, 1024, 0, stream>>>(
        totD, metaEx, ratio, cars_out, entered_out, N, B);
}

// Round 19
// 91.480 us; speedup vs baseline: 1.3080x; 1.3080x over previous
//
#include <hip/hip_runtime.h>
#include <stdint.h>

typedef _Float16 f16x8 __attribute__((ext_vector_type(8)));

#define RBITS 9
#define RSZ   512         // nodes per bucket
#define G     512         // edge chunks
#define MAXB  256         // max buckets (N <= 131072; s fits 17 bits)
#define CHMAX 3200        // >= ceil(E/G) = 3125
#define RMAX  7           // ceil(CHMAX/512)

// ---- block-wide exclusive scan (shuffles + wave totals); NT = block size ----
template<int NT>
__device__ __forceinline__ uint32_t scanExcl(uint32_t v, uint32_t* wtot, int t)
{
    uint32_t x = v;
    #pragma unroll
    for (int d = 1; d < 64; d <<= 1) {
        uint32_t y = __shfl_up(x, d, 64);
        if ((t & 63) >= d) x += y;
    }
    int w = t >> 6;
    if ((t & 63) == 63) wtot[w] = x;
    __syncthreads();
    uint32_t pre = 0;
    #pragma unroll
    for (int k = 0; k < NT / 64; ++k) pre += (k < w) ? wtot[k] : 0;
    return pre + x - v;
}

// ------- node+count, role-split: blocks < NB do node work ONLY; blocks >= NB
// count edge chunks (1-2 each). Removes the node-block tail imbalance.
__global__ __launch_bounds__(512) void nodecount_kernel(
    const int*   __restrict__ features,
    const float* __restrict__ cars,
    const float* __restrict__ entered,
    const float* __restrict__ free_,
    const float* __restrict__ embed_table,
    const float* __restrict__ W2n,   // 33
    const float* __restrict__ b2n,   // 1
    const float* __restrict__ W2e,   // 64x32
    const float* __restrict__ W3,    // 35x8
    const int* __restrict__ src, const int* __restrict__ dst,
    float* __restrict__ emb_out,     // N x 32
    float* __restrict__ cars1,       // N
    f16x8* __restrict__ Ah,          // N
    f16x8* __restrict__ Bh,          // N
    float* __restrict__ sfree,       // N: sign = free, magnitude = feature+1
    uint16_t* __restrict__ cntS, uint16_t* __restrict__ cntD,  // [B][G]
    int N, int E, int B)
{
    int t = threadIdx.x, g = blockIdx.x;
    int NB = (N + 511) >> 9;                 // node blocks (196)

    if (g >= NB) {
        // ---- counting role: chunks g-NB, g-NB+(G-NB), ... ----
        __shared__ uint32_t cS[MAXB], cD[MAXB];
        int per = (E + G - 1) / G;
        for (int chunk = g - NB; chunk < G; chunk += (G - NB)) {
            for (int i = t; i < MAXB; i += 512) { cS[i] = 0; cD[i] = 0; }
            __syncthreads();
            int lo = chunk * per, hi = min(E, lo + per);
            for (int i = lo + t; i < hi; i += 512) {
                atomicAdd(&cS[src[i] >> RBITS], 1u);
                atomicAdd(&cD[dst[i] >> RBITS], 1u);
            }
            __syncthreads();
            for (int i = t; i < B; i += 512) {
                cntS[(size_t)i * G + chunk] = (uint16_t)cS[i];
                cntD[(size_t)i * G + chunk] = (uint16_t)cD[i];
            }
            __syncthreads();
        }
        return;
    }

    // ---- node role ----
    __shared__ float Wa[256], Wb[256];
    if (t < 256) {
        int k = t >> 3, j = t & 7;   // t == k*8+j
        float a = 0.f, b = 0.f;
        #pragma unroll
        for (int m = 0; m < 32; ++m) {
            float w3 = W3[m * 8 + j];
            a += W2e[k * 32 + m]        * w3;
            b += W2e[(32 + k) * 32 + m] * w3;
        }
        Wa[t] = a;
        Wb[t] = b;
    }
    __syncthreads();

    int i = g * 512 + t;
    if (i >= N) return;
    int f = features[i];
    const float4* erow = (const float4*)(embed_table + (size_t)f * 32);
    float4* orow = (float4*)(emb_out + (size_t)i * 32);
    float e[32];
    #pragma unroll
    for (int q = 0; q < 8; ++q) {
        float4 v = erow[q];
        orow[q] = v;
        e[4*q+0] = v.x; e[4*q+1] = v.y; e[4*q+2] = v.z; e[4*q+3] = v.w;
    }
    float parked = b2n[0];
    #pragma unroll
    for (int k = 0; k < 32; ++k) parked += e[k] * W2n[k];
    float c = cars[i];
    parked += c * W2n[32];
    float c1 = fmaxf(fmaxf(parked, 0.f) + c, 0.f);
    cars1[i] = c1;
    float fm = (float)f + 1.f;                   // exact (< 2^24)
    sfree[i] = (free_[i] > 0.5f) ? -fm : fm;

    float ent = entered[i];
    float a8[8], b8[8];
    #pragma unroll
    for (int j = 0; j < 8; ++j) {
        a8[j] = c1 * W3[32*8 + j] + ent * W3[34*8 + j];
        b8[j] = c1 * W3[33*8 + j];
    }
    #pragma unroll
    for (int k = 0; k < 32; ++k) {
        float x = e[k];
        #pragma unroll
        for (int j = 0; j < 8; ++j) {
            a8[j] += x * Wa[k*8 + j];
            b8[j] += x * Wb[k*8 + j];
        }
    }
    f16x8 av, bv;
    #pragma unroll
    for (int j = 0; j < 8; ++j) { av[j] = (_Float16)a8[j]; bv[j] = (_Float16)b8[j]; }
    Ah[i] = av;
    Bh[i] = bv;
}

// -------- scanA: per-bucket exclusive scan over G chunks (1 block/bucket) ----
__global__ __launch_bounds__(512) void scanA_kernel(
    uint16_t* __restrict__ cntS, uint16_t* __restrict__ cntD,
    uint32_t* __restrict__ totS, uint32_t* __restrict__ totD, int B)
{
    __shared__ uint32_t wtot[8];
    int arr = (int)(blockIdx.x >= (unsigned)B);
    int b = blockIdx.x - (arr ? B : 0);
    uint16_t* a   = arr ? cntD : cntS;
    uint32_t* tot = arr ? totD : totS;
    int t = threadIdx.x;
    uint32_t v = a[(size_t)b * G + t];
    uint32_t e = scanExcl<512>(v, wtot, t);
    a[(size_t)b * G + t] = (uint16_t)e;
    if (t == G - 1) tot[b] = e + v;
}

// -------- scatter (fused): edge MLP once; bin by src AND by dst --------------
// min-waves=4 -> VGPR budget 128 so the hoisted gather arrays actually stay
// in registers (R13's attempt was silently capped at 64 VGPR and serialized).
__global__ __launch_bounds__(512, 4) void scatter_kernel(
    const int* __restrict__ src, const int* __restrict__ dst,
    const float* __restrict__ sfree,
    const f16x8* __restrict__ Ah, const f16x8* __restrict__ Bh,
    const float* __restrict__ b2e, const float* __restrict__ W3,
    const float* __restrict__ b3,  const float* __restrict__ W4,
    const float* __restrict__ b4,
    const uint16_t* __restrict__ cntS, const uint16_t* __restrict__ cntD,
    const uint32_t* __restrict__ totS, const uint32_t* __restrict__ totD,
    uint32_t* __restrict__ payloadS,   // E : s_local | exb<<16
    uint64_t* __restrict__ metaEx,     // E : (s | dloc<<17 | self<<31) | exb<<32
    int E, int B)
{
    __shared__ float b3p[8];
    __shared__ uint32_t curS[MAXB], curD[MAXB];
    __shared__ uint32_t tblS[MAXB], tblD[MAXB];   // hcnt -> hbase (in place)
    __shared__ uint32_t wtot[8];
    __shared__ union { uint32_t b32[CHMAX]; uint64_t b64[CHMAX]; } stg;
    __shared__ uint16_t bid[CHMAX];

    int t = threadIdx.x, g = blockIdx.x;
    // base prefixes from totals (values only on t < B <= 256)
    uint32_t vS = (t < B) ? totS[t] : 0;
    uint32_t eS = scanExcl<512>(vS, wtot, t);
    __syncthreads();
    uint32_t vD = (t < B) ? totD[t] : 0;
    uint32_t eD = scanExcl<512>(vD, wtot, t);
    if (t < B) {
        curS[t] = eS + cntS[(size_t)t * G + g];
        curD[t] = eD + cntD[(size_t)t * G + g];
    }
    if (t < MAXB) { tblS[t] = 0; tblD[t] = 0; }
    if (t < 8) {           // fold b2e@W3 into b3
        float s = b3[t];
        #pragma unroll
        for (int m = 0; m < 32; ++m) s += b2e[m] * W3[m * 8 + t];
        b3p[t] = s;
    }
    __syncthreads();
    float w4[8]; float bias4 = b4[0];
    #pragma unroll
    for (int j = 0; j < 8; ++j) w4[j] = W4[j];

    int per = (E + G - 1) / G;
    int lo = g * per, hi = min(E, lo + per), n = hi - lo;

    // ---- hoisted loads: indices, then all gathers (branchless via clamp) ----
    int   sA[RMAX], dA[RMAX];
    #pragma unroll
    for (int r = 0; r < RMAX; ++r) {
        int idx = min(r * 512 + t, n - 1);
        int i = lo + idx;
        sA[r] = src[i];
        dA[r] = dst[i];
    }
    f16x8 avA[RMAX], bvA[RMAX];
    float fsvA[RMAX], fdvA[RMAX];
    #pragma unroll
    for (int r = 0; r < RMAX; ++r) {
        avA[r]  = Ah[sA[r]];
        bvA[r]  = Bh[dA[r]];
        fsvA[r] = sfree[sA[r]];
        fdvA[r] = sfree[dA[r]];
    }

    // regA = keyS | rankS<<8 | self<<31 ; regB = keyD | rankD<<8 | dloc<<21
    // regC = s_local | exb<<16    (ranks < 3200: bits 8..19)
    uint32_t regA[RMAX], regB[RMAX], regC[RMAX];
    #pragma unroll
    for (int r = 0; r < RMAX; ++r) {
        int idx = r * 512 + t;
        int s = sA[r], d = dA[r];
        float out = bias4;
        #pragma unroll
        for (int j = 0; j < 8; ++j)
            out += fmaxf((float)avA[r][j] + (float)bvA[r][j] + b3p[j], 0.f) * w4[j];
        bool self  = (fabsf(fsvA[r]) == fabsf(fdvA[r]));
        bool freeS = (fsvA[r] < 0.f);
        float l = (self != freeS) ? fmaxf(out, 0.f) : 0.f;
        float ex = __expf(l);                 // l in [0,~6]: no overflow
        uint32_t exb = (uint32_t)__builtin_bit_cast(unsigned short, (_Float16)ex);
        if (idx < n) {
            uint32_t keyS = (uint32_t)s >> RBITS;
            uint32_t keyD = (uint32_t)d >> RBITS;
            uint32_t rankS = atomicAdd(&tblS[keyS], 1u);
            uint32_t rankD = atomicAdd(&tblD[keyD], 1u);
            regA[r] = keyS | (rankS << 8) | (self ? 0x80000000u : 0u);
            regB[r] = keyD | (rankD << 8) | ((uint32_t)(d & (RSZ - 1)) << 21);
            regC[r] = (uint32_t)(s & (RSZ - 1)) | (exb << 16);
        }
    }
    __syncthreads();
    uint32_t hS = (t < MAXB) ? tblS[t] : 0;
    uint32_t hD = (t < MAXB) ? tblD[t] : 0;
    __syncthreads();
    uint32_t bS = scanExcl<512>(hS, wtot, t);
    __syncthreads();
    uint32_t bD = scanExcl<512>(hD, wtot, t);
    if (t < MAXB) {
        tblS[t] = bS;      // now hbaseS
        tblD[t] = bD;      // now hbaseD
    }
    __syncthreads();

    // ---- phase S: place grouped (record bucket id), flush with computed addr
    #pragma unroll
    for (int r = 0; r < RMAX; ++r) {
        int idx = r * 512 + t;
        if (idx < n) {
            uint32_t key = regA[r] & 255u;
            uint32_t slot = tblS[key] + ((regA[r] >> 8) & 0xFFFu);
            stg.b32[slot] = regC[r];
            bid[slot] = (uint16_t)key;
        }
    }
    __syncthreads();
    for (int j = t; j < n; j += 512) {
        uint32_t b = bid[j];
        payloadS[curS[b] + (j - tblS[b])] = stg.b32[j];
    }
    __syncthreads();

    // ---- phase D: u64 records, single staged flush ----
    #pragma unroll
    for (int r = 0; r < RMAX; ++r) {
        int idx = r * 512 + t;
        if (idx < n) {
            uint32_t key = regB[r] & 255u;
            uint32_t slot = tblD[key] + ((regB[r] >> 8) & 0xFFFu);
            uint32_t s = ((regA[r] & 255u) << RBITS) | (regC[r] & (RSZ - 1));
            uint32_t mlo = s | (((regB[r] >> 21) & 0x1FFu) << 17)
                         | (regA[r] & 0x80000000u);
            stg.b64[slot] = (uint64_t)mlo | ((uint64_t)(regC[r] >> 16) << 32);
            bid[slot] = (uint16_t)key;
        }
    }
    __syncthreads();
    for (int j = t; j < n; j += 512) {
        uint32_t b = bid[j];
        metaEx[curD[b] + (j - tblD[b])] = stg.b64[j];
    }
}

// ---------------- bucketS: ssum via LDS, emit ratio = cars1/ssum -------------
__global__ __launch_bounds__(1024) void bucketS_kernel(
    const uint32_t* __restrict__ totS, const uint32_t* __restrict__ payloadS,
    const float* __restrict__ cars1, float* __restrict__ ratio,
    int N, int B)
{
    __shared__ float acc[RSZ];
    __shared__ uint32_t wtot[16];
    __shared__ uint32_t be[2];
    int b = blockIdx.x, t = threadIdx.x;
    uint32_t v = (t < B) ? totS[t] : 0;
    uint32_t e = scanExcl<1024>(v, wtot, t);
    if (t == b) { be[0] = e; be[1] = e + v; }
    for (int i = t; i < RSZ; i += 1024) acc[i] = 0.f;
    __syncthreads();
    uint32_t beg = be[0], end = be[1];
    for (uint32_t i = beg + t; i < end; i += 1024) {
        uint32_t p = payloadS[i];
        float val = (float)__builtin_bit_cast(_Float16, (unsigned short)(p >> 16));
        atomicAdd(&acc[p & (RSZ - 1)], val);       // ds_add_f32
    }
    __syncthreads();
    int nb = b << RBITS;
    for (int i = t; i < RSZ; i += 1024) {
        int node = nb + i;
        if (node < N) {
            float s = acc[i];
            ratio[node] = cars1[node] / (s > 0.f ? s : 1.f);  // unused if deg 0
        }
    }
}

// ------- bucketD: cars/delta via LDS, write cars_out & entered_out -----------
__global__ __launch_bounds__(1024) void bucketD_kernel(
    const uint32_t* __restrict__ totD,
    const uint64_t* __restrict__ metaEx,
    const float* __restrict__ ratio,
    float* __restrict__ cars_out, float* __restrict__ entered_out,
    int N, int B)
{
    __shared__ float accC[RSZ], accX[RSZ];
    __shared__ uint32_t wtot[16];
    __shared__ uint32_t be[2];
    int b = blockIdx.x, t = threadIdx.x;
    uint32_t v = (t < B) ? totD[t] : 0;
    uint32_t e = scanExcl<1024>(v, wtot, t);
    if (t == b) { be[0] = e; be[1] = e + v; }
    for (int i = t; i < RSZ; i += 1024) { accC[i] = 0.f; accX[i] = 0.f; }
    __syncthreads();
    uint32_t beg = be[0], end = be[1];
    for (uint32_t i = beg + t; i < end; i += 1024) {
        uint64_t me = metaEx[i];
        uint32_t m = (uint32_t)me;
        float ex = (float)__builtin_bit_cast(_Float16, (unsigned short)(me >> 32));
        int s  = m & 0x1FFFF;
        int ld = (m >> 17) & (RSZ - 1);
        float c = ratio[s] * ex;
        atomicAdd(&accC[ld], c);
        if (m & 0x80000000u) atomicAdd(&accX[ld], c);   // selfloop
    }
    __syncthreads();
    int nb = b << RBITS;
    for (int i = t; i < RSZ; i += 1024) {
        int node = nb + i;
        if (node < N) {
            float cs = accC[i];
            cars_out[node]    = cs;
            entered_out[node] = cs - accX[i];
        }
    }
}

extern "C" void kernel_launch(void* const* d_in, const int* in_sizes, int n_in,
                              void* d_out, int out_size, void* d_ws, size_t ws_size,
                              hipStream_t stream)
{
    const int N = in_sizes[0];     // 100000
    const int E = in_sizes[4];     // 1600000
    const int B = (N + RSZ - 1) / RSZ;     // 196 buckets
    const int L = B * G;

    const int*   features    = (const int*)  d_in[0];
    const float* cars        = (const float*)d_in[1];
    const float* entered     = (const float*)d_in[2];
    const float* free_       = (const float*)d_in[3];
    const int*   src         = (const int*)  d_in[4];
    const int*   dst         = (const int*)  d_in[5];
    const float* embed_table = (const float*)d_in[6];
    const float* W2n         = (const float*)d_in[7];
    const float* b2n         = (const float*)d_in[8];
    const float* W2e         = (const float*)d_in[9];
    const float* b2e         = (const float*)d_in[10];
    const float* W3          = (const float*)d_in[11];
    const float* b3          = (const float*)d_in[12];
    const float* W4          = (const float*)d_in[13];
    const float* b4          = (const float*)d_in[14];

    float* out         = (float*)d_out;
    float* cars_out    = out;                       // N
    float* emb_out     = out + N;                   // N*32
    float* entered_out = out + (size_t)N * 33;      // N

    // workspace layout (float offsets; Ah at 4N -> 16B aligned)
    float*    ws       = (float*)d_ws;
    float*    cars1    = ws;                              // N
    float*    ratio    = ws + N;                          // N
    float*    sfree    = ws + (size_t)2 * N;              // N (signed feat)
    f16x8*    Ah       = (f16x8*)(ws + (size_t)4 * N);    // N*16B
    f16x8*    Bh       = (f16x8*)(ws + (size_t)8 * N);    // N*16B
    uint32_t* totS     = (uint32_t*)(ws + (size_t)12 * N);// B
    uint32_t* totD     = totS + MAXB;                     // B
    // metaEx first for 8B alignment (12N + 512 floats -> even)
    uint64_t* metaEx   = (uint64_t*)(totD + MAXB);        // E u64
    uint32_t* payloadS = (uint32_t*)(metaEx + E);         // E u32
    uint16_t* cntS     = (uint16_t*)(payloadS + E);       // L u16
    uint16_t* cntD     = cntS + L;                        // L u16

    nodecount_kernel<<<G, 512, 0, stream>>>(
        features, cars, entered, free_, embed_table, W2n, b2n, W2e, W3,
        src, dst, emb_out, cars1, Ah, Bh, sfree, cntS, cntD, N, E, B);
    scanA_kernel<<<2 * B, 512, 0, stream>>>(cntS, cntD, totS, totD, B);
    scatter_kernel<<<G, 512, 0, stream>>>(
        src, dst, sfree, Ah, Bh, b2e, W3, b3, W4, b4,
        cntS, cntD, totS, totD, payloadS, metaEx, E, B);
    bucketS_kernel<<<B, 1024, 0, stream>>>(totS, payloadS, cars1, ratio, N, B);
    bucketD_kernel<<<B, 1024, 0, stream>>>(
        totD, metaEx, ratio, cars_out, entered_out, N, B);
}

// Round 21
// 89.172 us; speedup vs baseline: 1.3419x; 1.0259x over previous
//
#include <hip/hip_runtime.h>
#include <stdint.h>

typedef _Float16 f16x8 __attribute__((ext_vector_type(8)));

#define RBITS 9
#define RSZ   512         // nodes per bucket
#define G     512         // edge chunks (one block each)
#define MAXB  256         // max buckets (N <= 131072; s fits 17 bits)
#define CHMAX 3200        // >= ceil(E/G) = 3125
#define RMAX  7           // ceil(CHMAX/512)

// ---- block-wide exclusive scan (shuffles + wave totals); NT = block size ----
template<int NT>
__device__ __forceinline__ uint32_t scanExcl(uint32_t v, uint32_t* wtot, int t)
{
    uint32_t x = v;
    #pragma unroll
    for (int d = 1; d < 64; d <<= 1) {
        uint32_t y = __shfl_up(x, d, 64);
        if ((t & 63) >= d) x += y;
    }
    int w = t >> 6;
    if ((t & 63) == 63) wtot[w] = x;
    __syncthreads();
    uint32_t pre = 0;
    #pragma unroll
    for (int k = 0; k < NT / 64; ++k) pre += (k < w) ? wtot[k] : 0;
    return pre + x - v;
}

// ------- fused node+count: grid = G blocks; all count, low blocks do node ----
__global__ __launch_bounds__(512) void nodecount_kernel(
    const int*   __restrict__ features,
    const float* __restrict__ cars,
    const float* __restrict__ entered,
    const float* __restrict__ free_,
    const float* __restrict__ embed_table,
    const float* __restrict__ W2n,   // 33
    const float* __restrict__ b2n,   // 1
    const float* __restrict__ W2e,   // 64x32
    const float* __restrict__ W3,    // 35x8
    const int* __restrict__ src, const int* __restrict__ dst,
    float* __restrict__ emb_out,     // N x 32
    float* __restrict__ cars1,       // N
    f16x8* __restrict__ Ah,          // N
    f16x8* __restrict__ Bh,          // N
    float* __restrict__ sfree,       // N: sign = free, magnitude = feature+1
    uint16_t* __restrict__ cntS, uint16_t* __restrict__ cntD,  // [B][G]
    int N, int E, int B)
{
    __shared__ uint32_t cS[MAXB], cD[MAXB];
    int t = threadIdx.x, g = blockIdx.x;
    for (int i = t; i < MAXB; i += 512) { cS[i] = 0; cD[i] = 0; }
    __syncthreads();
    int per = (E + G - 1) / G;
    int lo = g * per, hi = min(E, lo + per);
    for (int i = lo + t; i < hi; i += 512) {
        atomicAdd(&cS[src[i] >> RBITS], 1u);
        atomicAdd(&cD[dst[i] >> RBITS], 1u);
    }
    __syncthreads();
    for (int i = t; i < B; i += 512) {
        cntS[(size_t)i * G + g] = (uint16_t)cS[i];
        cntD[(size_t)i * G + g] = (uint16_t)cD[i];
    }

    // ---- node part (blocks covering node range only) ----
    if (g * 512 >= N) return;
    __shared__ float Wa[256], Wb[256];
    if (t < 256) {
        int k = t >> 3, j = t & 7;   // t == k*8+j
        float a = 0.f, b = 0.f;
        #pragma unroll
        for (int m = 0; m < 32; ++m) {
            float w3 = W3[m * 8 + j];
            a += W2e[k * 32 + m]        * w3;
            b += W2e[(32 + k) * 32 + m] * w3;
        }
        Wa[t] = a;
        Wb[t] = b;
    }
    __syncthreads();

    int i = g * 512 + t;
    if (i >= N) return;
    int f = features[i];
    const float4* erow = (const float4*)(embed_table + (size_t)f * 32);
    float4* orow = (float4*)(emb_out + (size_t)i * 32);
    float e[32];
    #pragma unroll
    for (int q = 0; q < 8; ++q) {
        float4 v = erow[q];
        orow[q] = v;
        e[4*q+0] = v.x; e[4*q+1] = v.y; e[4*q+2] = v.z; e[4*q+3] = v.w;
    }
    float parked = b2n[0];
    #pragma unroll
    for (int k = 0; k < 32; ++k) parked += e[k] * W2n[k];
    float c = cars[i];
    parked += c * W2n[32];
    float c1 = fmaxf(fmaxf(parked, 0.f) + c, 0.f);
    cars1[i] = c1;
    float fm = (float)f + 1.f;                   // exact (< 2^24)
    sfree[i] = (free_[i] > 0.5f) ? -fm : fm;

    float ent = entered[i];
    float a8[8], b8[8];
    #pragma unroll
    for (int j = 0; j < 8; ++j) {
        a8[j] = c1 * W3[32*8 + j] + ent * W3[34*8 + j];
        b8[j] = c1 * W3[33*8 + j];
    }
    #pragma unroll
    for (int k = 0; k < 32; ++k) {
        float x = e[k];
        #pragma unroll
        for (int j = 0; j < 8; ++j) {
            a8[j] += x * Wa[k*8 + j];
            b8[j] += x * Wb[k*8 + j];
        }
    }
    f16x8 av, bv;
    #pragma unroll
    for (int j = 0; j < 8; ++j) { av[j] = (_Float16)a8[j]; bv[j] = (_Float16)b8[j]; }
    Ah[i] = av;
    Bh[i] = bv;
}

// -------- scanA: per-bucket exclusive scan over G chunks (1 block/bucket) ----
__global__ __launch_bounds__(512) void scanA_kernel(
    uint16_t* __restrict__ cntS, uint16_t* __restrict__ cntD,
    uint32_t* __restrict__ totS, uint32_t* __restrict__ totD, int B)
{
    __shared__ uint32_t wtot[8];
    int arr = (int)(blockIdx.x >= (unsigned)B);
    int b = blockIdx.x - (arr ? B : 0);
    uint16_t* a   = arr ? cntD : cntS;
    uint32_t* tot = arr ? totD : totS;
    int t = threadIdx.x;
    uint32_t v = a[(size_t)b * G + t];
    uint32_t e = scanExcl<512>(v, wtot, t);
    a[(size_t)b * G + t] = (uint16_t)e;
    if (t == G - 1) tot[b] = e + v;
}

// -------- scatter (fused): edge MLP once; bin by src AND by dst --------------
// Branchless hoisted gathers before dependent compute.
__global__ __launch_bounds__(512) void scatter_kernel(
    const int* __restrict__ src, const int* __restrict__ dst,
    const float* __restrict__ sfree,
    const f16x8* __restrict__ Ah, const f16x8* __restrict__ Bh,
    const float* __restrict__ b2e, const float* __restrict__ W3,
    const float* __restrict__ b3,  const float* __restrict__ W4,
    const float* __restrict__ b4,
    const uint16_t* __restrict__ cntS, const uint16_t* __restrict__ cntD,
    const uint32_t* __restrict__ totS, const uint32_t* __restrict__ totD,
    uint32_t* __restrict__ payloadS,   // E : s_local | exb<<16
    uint64_t* __restrict__ metaEx,     // E : (s | dloc<<17 | self<<31) | exb<<32
    int E, int B)
{
    __shared__ float b3p[8];
    __shared__ uint32_t curS[MAXB], curD[MAXB];
    __shared__ uint32_t tblS[MAXB], tblD[MAXB];   // hcnt -> hbase (in place)
    __shared__ uint32_t wtot[8];
    __shared__ union { uint32_t b32[CHMAX]; uint64_t b64[CHMAX]; } stg;
    __shared__ uint16_t bid[CHMAX];

    int t = threadIdx.x, g = blockIdx.x;
    // base prefixes from totals (values only on t < B <= 256)
    uint32_t vS = (t < B) ? totS[t] : 0;
    uint32_t eS = scanExcl<512>(vS, wtot, t);
    __syncthreads();
    uint32_t vD = (t < B) ? totD[t] : 0;
    uint32_t eD = scanExcl<512>(vD, wtot, t);
    if (t < B) {
        curS[t] = eS + cntS[(size_t)t * G + g];
        curD[t] = eD + cntD[(size_t)t * G + g];
    }
    if (t < MAXB) { tblS[t] = 0; tblD[t] = 0; }
    if (t < 8) {           // fold b2e@W3 into b3
        float s = b3[t];
        #pragma unroll
        for (int m = 0; m < 32; ++m) s += b2e[m] * W3[m * 8 + t];
        b3p[t] = s;
    }
    __syncthreads();
    float w4[8]; float bias4 = b4[0];
    #pragma unroll
    for (int j = 0; j < 8; ++j) w4[j] = W4[j];

    int per = (E + G - 1) / G;
    int lo = g * per, hi = min(E, lo + per), n = hi - lo;

    // ---- hoisted loads: indices, then all gathers (branchless via clamp) ----
    int   sA[RMAX], dA[RMAX];
    #pragma unroll
    for (int r = 0; r < RMAX; ++r) {
        int idx = min(r * 512 + t, n - 1);
        int i = lo + idx;
        sA[r] = src[i];
        dA[r] = dst[i];
    }
    f16x8 avA[RMAX], bvA[RMAX];
    float fsvA[RMAX], fdvA[RMAX];
    #pragma unroll
    for (int r = 0; r < RMAX; ++r) {
        avA[r]  = Ah[sA[r]];
        bvA[r]  = Bh[dA[r]];
        fsvA[r] = sfree[sA[r]];
        fdvA[r] = sfree[dA[r]];
    }

    // regA = keyS | rankS<<8 | self<<31 ; regB = keyD | rankD<<8 | dloc<<21
    // regC = s_local | exb<<16    (ranks < 3200: bits 8..19)
    uint32_t regA[RMAX], regB[RMAX], regC[RMAX];
    #pragma unroll
    for (int r = 0; r < RMAX; ++r) {
        int idx = r * 512 + t;
        int s = sA[r], d = dA[r];
        float out = bias4;
        #pragma unroll
        for (int j = 0; j < 8; ++j)
            out += fmaxf((float)avA[r][j] + (float)bvA[r][j] + b3p[j], 0.f) * w4[j];
        bool self  = (fabsf(fsvA[r]) == fabsf(fdvA[r]));
        bool freeS = (fsvA[r] < 0.f);
        float l = (self != freeS) ? fmaxf(out, 0.f) : 0.f;
        float ex = __expf(l);                 // l in [0,~6]: no overflow
        uint32_t exb = (uint32_t)__builtin_bit_cast(unsigned short, (_Float16)ex);
        if (idx < n) {
            uint32_t keyS = (uint32_t)s >> RBITS;
            uint32_t keyD = (uint32_t)d >> RBITS;
            uint32_t rankS = atomicAdd(&tblS[keyS], 1u);
            uint32_t rankD = atomicAdd(&tblD[keyD], 1u);
            regA[r] = keyS | (rankS << 8) | (self ? 0x80000000u : 0u);
            regB[r] = keyD | (rankD << 8) | ((uint32_t)(d & (RSZ - 1)) << 21);
            regC[r] = (uint32_t)(s & (RSZ - 1)) | (exb << 16);
        }
    }
    __syncthreads();
    uint32_t hS = (t < MAXB) ? tblS[t] : 0;
    uint32_t hD = (t < MAXB) ? tblD[t] : 0;
    __syncthreads();
    uint32_t bS = scanExcl<512>(hS, wtot, t);
    __syncthreads();
    uint32_t bD = scanExcl<512>(hD, wtot, t);
    if (t < MAXB) {
        tblS[t] = bS;      // now hbaseS
        tblD[t] = bD;      // now hbaseD
    }
    __syncthreads();

    // ---- phase S: place grouped (record bucket id), flush with computed addr
    #pragma unroll
    for (int r = 0; r < RMAX; ++r) {
        int idx = r * 512 + t;
        if (idx < n) {
            uint32_t key = regA[r] & 255u;
            uint32_t slot = tblS[key] + ((regA[r] >> 8) & 0xFFFu);
            stg.b32[slot] = regC[r];
            bid[slot] = (uint16_t)key;
        }
    }
    __syncthreads();
    for (int j = t; j < n; j += 512) {
        uint32_t b = bid[j];
        payloadS[curS[b] + (j - tblS[b])] = stg.b32[j];
    }
    __syncthreads();

    // ---- phase D: u64 records, single staged flush ----
    #pragma unroll
    for (int r = 0; r < RMAX; ++r) {
        int idx = r * 512 + t;
        if (idx < n) {
            uint32_t key = regB[r] & 255u;
            uint32_t slot = tblD[key] + ((regB[r] >> 8) & 0xFFFu);
            uint32_t s = ((regA[r] & 255u) << RBITS) | (regC[r] & (RSZ - 1));
            uint32_t mlo = s | (((regB[r] >> 21) & 0x1FFu) << 17)
                         | (regA[r] & 0x80000000u);
            stg.b64[slot] = (uint64_t)mlo | ((uint64_t)(regC[r] >> 16) << 32);
            bid[slot] = (uint16_t)key;
        }
    }
    __syncthreads();
    for (int j = t; j < n; j += 512) {
        uint32_t b = bid[j];
        metaEx[curD[b] + (j - tblD[b])] = stg.b64[j];
    }
}

// ---------------- bucketS: ssum via LDS, emit ratio = cars1/ssum -------------
__global__ __launch_bounds__(1024) void bucketS_kernel(
    const uint32_t* __restrict__ totS, const uint32_t* __restrict__ payloadS,
    const float* __restrict__ cars1, float* __restrict__ ratio,
    int N, int B)
{
    __shared__ float acc[RSZ];
    __shared__ uint32_t wtot[16];
    __shared__ uint32_t be[2];
    int b = blockIdx.x, t = threadIdx.x;
    uint32_t v = (t < B) ? totS[t] : 0;
    uint32_t e = scanExcl<1024>(v, wtot, t);
    if (t == b) { be[0] = e; be[1] = e + v; }
    for (int i = t; i < RSZ; i += 1024) acc[i] = 0.f;
    __syncthreads();
    uint32_t beg = be[0], end = be[1];
    for (uint32_t i = beg + t; i < end; i += 1024) {
        uint32_t p = payloadS[i];
        float val = (float)__builtin_bit_cast(_Float16, (unsigned short)(p >> 16));
        atomicAdd(&acc[p & (RSZ - 1)], val);       // ds_add_f32
    }
    __syncthreads();
    int nb = b << RBITS;
    for (int i = t; i < RSZ; i += 1024) {
        int node = nb + i;
        if (node < N) {
            float s = acc[i];
            ratio[node] = cars1[node] / (s > 0.f ? s : 1.f);  // unused if deg 0
        }
    }
}

// ------- bucketD: cars/delta via LDS, write cars_out & entered_out -----------
__global__ __launch_bounds__(1024) void bucketD_kernel(
    const uint32_t* __restrict__ totD,
    const uint64_t* __restrict__ metaEx,
    const float* __restrict__ ratio,
    float* __restrict__ cars_out, float* __restrict__ entered_out,
    int N, int B)
{
    __shared__ float accC[RSZ], accX[RSZ];
    __shared__ uint32_t wtot[16];
    __shared__ uint32_t be[2];
    int b = blockIdx.x, t = threadIdx.x;
    uint32_t v = (t < B) ? totD[t] : 0;
    uint32_t e = scanExcl<1024>(v, wtot, t);
    if (t == b) { be[0] = e; be[1] = e + v; }
    for (int i = t; i < RSZ; i += 1024) { accC[i] = 0.f; accX[i] = 0.f; }
    __syncthreads();
    uint32_t beg = be[0], end = be[1];
    for (uint32_t i = beg + t; i < end; i += 1024) {
        uint64_t me = metaEx[i];
        uint32_t m = (uint32_t)me;
        float ex = (float)__builtin_bit_cast(_Float16, (unsigned short)(me >> 32));
        int s  = m & 0x1FFFF;
        int ld = (m >> 17) & (RSZ - 1);
        float c = ratio[s] * ex;
        atomicAdd(&accC[ld], c);
        if (m & 0x80000000u) atomicAdd(&accX[ld], c);   // selfloop
    }
    __syncthreads();
    int nb = b << RBITS;
    for (int i = t; i < RSZ; i += 1024) {
        int node = nb + i;
        if (node < N) {
            float cs = accC[i];
            cars_out[node]    = cs;
            entered_out[node] = cs - accX[i];
        }
    }
}

extern "C" void kernel_launch(void* const* d_in, const int* in_sizes, int n_in,
                              void* d_out, int out_size, void* d_ws, size_t ws_size,
                              hipStream_t stream)
{
    const int N = in_sizes[0];     // 100000
    const int E = in_sizes[4];     // 1600000
    const int B = (N + RSZ - 1) / RSZ;     // 196 buckets
    const int L = B * G;

    const int*   features    = (const int*)  d_in[0];
    const float* cars        = (const float*)d_in[1];
    const float* entered     = (const float*)d_in[2];
    const float* free_       = (const float*)d_in[3];
    const int*   src         = (const int*)  d_in[4];
    const int*   dst         = (const int*)  d_in[5];
    const float* embed_table = (const float*)d_in[6];
    const float* W2n         = (const float*)d_in[7];
    const float* b2n         = (const float*)d_in[8];
    const float* W2e         = (const float*)d_in[9];
    const float* b2e         = (const float*)d_in[10];
    const float* W3          = (const float*)d_in[11];
    const float* b3          = (const float*)d_in[12];
    const float* W4          = (const float*)d_in[13];
    const float* b4          = (const float*)d_in[14];

    float* out         = (float*)d_out;
    float* cars_out    = out;                       // N
    float* emb_out     = out + N;                   // N*32
    float* entered_out = out + (size_t)N * 33;      // N

    // workspace layout (float offsets; Ah at 4N -> 16B aligned)
    float*    ws       = (float*)d_ws;
    float*    cars1    = ws;                              // N
    float*    ratio    = ws + N;                          // N
    float*    sfree    = ws + (size_t)2 * N;              // N (signed feat)
    f16x8*    Ah       = (f16x8*)(ws + (size_t)4 * N);    // N*16B
    f16x8*    Bh       = (f16x8*)(ws + (size_t)8 * N);    // N*16B
    uint32_t* totS     = (uint32_t*)(ws + (size_t)12 * N);// B
    uint32_t* totD     = totS + MAXB;                     // B
    // metaEx first for 8B alignment (12N + 512 floats -> even)
    uint64_t* metaEx   = (uint64_t*)(totD + MAXB);        // E u64
    uint32_t* payloadS = (uint32_t*)(metaEx + E);         // E u32
    uint16_t* cntS     = (uint16_t*)(payloadS + E);       // L u16
    uint16_t* cntD     = cntS + L;                        // L u16

    nodecount_kernel<<<G, 512, 0, stream>>>(
        features, cars, entered, free_, embed_table, W2n, b2n, W2e, W3,
        src, dst, emb_out, cars1, Ah, Bh, sfree, cntS, cntD, N, E, B);
    scanA_kernel<<<2 * B, 512, 0, stream>>>(cntS, cntD, totS, totD, B);
    scatter_kernel<<<G, 512, 0, stream>>>(
        src, dst, sfree, Ah, Bh, b2e, W3, b3, W4, b4,
        cntS, cntD, totS, totD, payloadS, metaEx, E, B);
    bucketS_kernel<<<B, 1024, 0, stream>>>(totS, payloadS, cars1, ratio, N, B);
    bucketD_kernel<<<B, 1024, 0, stream>>>(
        totD, metaEx, ratio, cars_out, entered_out, N, B);
}